// Round 1
// baseline (280.470 us; speedup 1.0000x reference)
//
#include <hip/hip_runtime.h>

typedef __attribute__((ext_vector_type(8))) short short8;
typedef __attribute__((ext_vector_type(4))) float f32x4;
typedef __attribute__((ext_vector_type(16))) float f32x16;

#define B_ROWS 16384

__device__ __forceinline__ float bf2f(ushort u){ return __uint_as_float(((uint)u)<<16); }
__device__ __forceinline__ ushort f2bf(float f){
  uint u = __float_as_uint(f);
  u = u + 0x7FFFu + ((u>>16)&1u);
  return (ushort)(u>>16);
}
__device__ __forceinline__ void gload_lds16(const void* g, void* l){
  __builtin_amdgcn_global_load_lds((const __attribute__((address_space(1))) unsigned*)g,
                                   (__attribute__((address_space(3))) unsigned*)l, 16, 0, 0);
}

// ---------------- weight transpose+convert: out[n*Kp+k] = bf16(in[k*N+n]) (0-pad k>=K)
__global__ __launch_bounds__(256) void transp(const float* __restrict__ in, ushort* __restrict__ out,
                                              int K, int N, int Kp)
{
  int i = blockIdx.x*256 + threadIdx.x;
  if (i >= N*Kp) return;
  int n = i / Kp, k = i - n*Kp;
  out[i] = (k < K) ? f2bf(in[(size_t)k*N + n]) : (ushort)0;
}

// ---------------- bottom layer 0: (B,13) @ (13,512) + b, relu -> bf16
__global__ __launch_bounds__(256) void bot0(const float* __restrict__ x, const float* __restrict__ W,
                                            const float* __restrict__ bias, ushort* __restrict__ out)
{
  int i = blockIdx.x*256 + threadIdx.x;
  int b = i>>9, n = i&511;
  const float* xr = x + (size_t)b*13;
  float s = bias[n];
  #pragma unroll
  for (int k=0;k<13;k++) s += xr[k]*W[k*512+n];
  out[i] = f2bf(fmaxf(s,0.f));
}

// ---------------- m97-style bf16 GEMM: C(MxN) = relu(A(MxK) @ Bt(NxK)^T + bias), all bf16, fp32 accum
template<bool RELU>
__global__ __launch_bounds__(256) void gemm_bt(const ushort* __restrict__ A,
    const ushort* __restrict__ Bt, const float* __restrict__ bias,
    ushort* __restrict__ C, int M, int N, int K)
{
  constexpr int BM=128, BN=128, BK=64;
  __shared__ __align__(16) ushort lA[BM*BK];
  __shared__ __align__(16) ushort lB[BN*BK];
  const int tid = threadIdx.x;
  const int wave = tid>>6, lane = tid&63;
  const int bm = blockIdx.x*BM, bn = blockIdx.y*BN;
  const int wrr = (wave>>1)*64, wcc = (wave&1)*64;
  const int lr = lane&15, lg = lane>>4;

  f32x4 acc[4][4];
  #pragma unroll
  for (int m=0;m<4;m++)
    #pragma unroll
    for (int n=0;n<4;n++)
      #pragma unroll
      for (int j=0;j<4;j++) acc[m][n][j] = 0.f;

  for (int k0=0;k0<K;k0+=BK){
    __syncthreads();
    #pragma unroll
    for (int c=0;c<4;c++){
      int s = wave*4 + c;
      int ob = s*1024 + lane*16;      // byte offset within 16KB tile
      int row = ob>>7, colb = ob&127; // 128 B per row (64 bf16)
      gload_lds16((const char*)A  + (((size_t)(bm+row)*K + k0)<<1) + colb, (char*)lA + ob);
      gload_lds16((const char*)Bt + (((size_t)(bn+row)*K + k0)<<1) + colb, (char*)lB + ob);
    }
    __syncthreads();
    #pragma unroll
    for (int kk=0;kk<BK;kk+=32){
      short8 af[4], bfr[4];
      const int lk = kk + lg*8;
      #pragma unroll
      for (int m=0;m<4;m++) af[m]  = *(const short8*)&lA[(wrr+m*16+lr)*BK + lk];
      #pragma unroll
      for (int n=0;n<4;n++) bfr[n] = *(const short8*)&lB[(wcc+n*16+lr)*BK + lk];
      #pragma unroll
      for (int m=0;m<4;m++)
        #pragma unroll
        for (int n=0;n<4;n++)
          acc[m][n] = __builtin_amdgcn_mfma_f32_16x16x32_bf16(af[m], bfr[n], acc[m][n], 0,0,0);
    }
  }
  // epilogue: C/D layout col=lane&15, row=(lane>>4)*4+j
  #pragma unroll
  for (int n=0;n<4;n++){
    int col = bn + wcc + n*16 + lr;
    float bv = bias[col];
    #pragma unroll
    for (int m=0;m<4;m++){
      #pragma unroll
      for (int j=0;j<4;j++){
        int row = bm + wrr + m*16 + lg*4 + j;
        float v = acc[m][n][j] + bv;
        if (RELU) v = fmaxf(v,0.f);
        C[(size_t)row*N + col] = f2bf(v);
      }
    }
  }
}

// ---------------- embedding gather + pairwise interaction -> R (B x 512 bf16)
// R[b][0:128]=x, R[b][128+p]=Z[LI[p],LJ[p]], R[b][479:512]=0
__global__ __launch_bounds__(256) void interact(const ushort* __restrict__ xb,
    const int* __restrict__ idx, const float* __restrict__ emb,
    ushort* __restrict__ R)
{
  __shared__ __align__(16) ushort Tl[4][32][136];   // 136 = 128 + pad (16B-aligned rows)
  const int w = threadIdx.x>>6, l = threadIdx.x&63;
  const int b = blockIdx.x*4 + w;

  // row 0 = x (already bf16); also copy to R[0:128]
  uint xv = ((const uint*)(xb + (size_t)b*128))[l];
  *(uint*)&Tl[w][0][2*l] = xv;
  ((uint*)(R + (size_t)b*512))[l] = xv;

  int myidx = (l<26) ? idx[(size_t)l*B_ROWS + b] : 0;
  #pragma unroll 1
  for (int t=0;t<26;t++){
    int e = __shfl(myidx, t);
    const float2* rp = (const float2*)(emb + ((size_t)t*50000 + (size_t)e)*128);
    float2 v = rp[l];
    uint pk = (uint)f2bf(v.x) | ((uint)f2bf(v.y)<<16);
    *(uint*)&Tl[w][t+1][2*l] = pk;
  }
  __syncthreads();

  // Z = T @ T^T via 32x32x16 bf16 MFMA; A-frag == B-frag for symmetric product
  f32x16 acc;
  #pragma unroll
  for (int i=0;i<16;i++) acc[i] = 0.f;
  #pragma unroll
  for (int kk=0;kk<8;kk++){
    short8 fa = *(const short8*)((const char*)&Tl[w][0][0] + (size_t)(l&31)*272 + kk*32 + (l>>5)*16);
    acc = __builtin_amdgcn_mfma_f32_32x32x16_bf16(fa, fa, acc, 0,0,0);
  }

  ushort* Rrow = R + (size_t)b*512;
  const int c = l&31;
  #pragma unroll
  for (int j=0;j<16;j++){
    int r = (j&3) + 8*(j>>2) + 4*(l>>5);   // C/D layout: col=lane&31, row=(reg&3)+8*(reg>>2)+4*(lane>>5)
    if (c < r && r <= 26) Rrow[128 + r*(r-1)/2 + c] = f2bf(acc[j]);
  }
  if (l < 33) Rrow[479 + l] = 0;
}

// ---------------- final: sigmoid(h3 @ w + b), clip -> fp32 out
__global__ __launch_bounds__(256) void finlayer(const ushort* __restrict__ h3,
    const ushort* __restrict__ wt, const float* __restrict__ b3, float* __restrict__ out)
{
  int w = threadIdx.x>>6, l = threadIdx.x&63;
  int b = blockIdx.x*4 + w;
  short8 hv = *(const short8*)(h3 + (size_t)b*512 + l*8);
  short8 wv = *(const short8*)(wt + l*8);
  float s = 0.f;
  #pragma unroll
  for (int j=0;j<8;j++) s += bf2f((ushort)hv[j])*bf2f((ushort)wv[j]);
  #pragma unroll
  for (int off=32; off>0; off>>=1) s += __shfl_xor(s, off);
  if (l==0){
    float h = s + b3[0];
    float p = 1.f/(1.f + expf(-h));
    out[b] = fminf(fmaxf(p, 0.f), 1.f);
  }
}

extern "C" void kernel_launch(void* const* d_in, const int* in_sizes, int n_in,
                              void* d_out, int out_size, void* d_ws, size_t ws_size,
                              hipStream_t stream)
{
  const float* dense_x = (const float*)d_in[0];
  const int*   indices = (const int*)d_in[1];
  const float* emb     = (const float*)d_in[2];
  const float* bW1 = (const float*)d_in[5];  const float* bb1 = (const float*)d_in[6];
  const float* bW2 = (const float*)d_in[7];  const float* bb2 = (const float*)d_in[8];
  const float* tW0 = (const float*)d_in[9];  const float* tb0 = (const float*)d_in[10];
  const float* tW1 = (const float*)d_in[11]; const float* tb1 = (const float*)d_in[12];
  const float* tW2 = (const float*)d_in[13]; const float* tb2 = (const float*)d_in[14];
  const float* tW3 = (const float*)d_in[15]; const float* tb3 = (const float*)d_in[16];
  const float* bW0 = (const float*)d_in[3];  const float* bb0 = (const float*)d_in[4];
  float* out = (float*)d_out;
  const int Bn = B_ROWS;

  char* ws = (char*)d_ws;
  size_t o = 0;
  auto alloc = [&](size_t bytes)->char*{ char* r = ws + o; o += (bytes + 255) & ~(size_t)255; return r; };
  ushort* wtB1 = (ushort*)alloc(256*512*2);       // bot_W1^T  (256 x 512)
  ushort* wtB2 = (ushort*)alloc(128*256*2);       // bot_W2^T  (128 x 256)
  ushort* wtT0 = (ushort*)alloc(1024*512*2);      // top_W0^T  (1024 x 512, K padded 479->512)
  ushort* wtT1 = (ushort*)alloc((size_t)1024*1024*2);
  ushort* wtT2 = (ushort*)alloc(512*1024*2);
  ushort* wtT3 = (ushort*)alloc(512*2);
  ushort* P    = (ushort*)alloc((size_t)Bn*512*2);  // act0 -> R -> h3 (reused)
  ushort* act1 = (ushort*)alloc((size_t)Bn*256*2);
  ushort* xb   = (ushort*)alloc((size_t)Bn*128*2);
  ushort* h1   = (ushort*)alloc((size_t)Bn*1024*2);
  ushort* h2   = (ushort*)alloc((size_t)Bn*1024*2);
  (void)ws_size; (void)in_sizes; (void)n_in; (void)out_size;

  // weight prep
  transp<<<512 ,256,0,stream>>>(bW1, wtB1, 512 ,256 ,512 );
  transp<<<128 ,256,0,stream>>>(bW2, wtB2, 256 ,128 ,256 );
  transp<<<2048,256,0,stream>>>(tW0, wtT0, 479 ,1024,512 );
  transp<<<4096,256,0,stream>>>(tW1, wtT1, 1024,1024,1024);
  transp<<<2048,256,0,stream>>>(tW2, wtT2, 1024,512 ,1024);
  transp<<<2   ,256,0,stream>>>(tW3, wtT3, 512 ,1   ,512 );

  // bottom MLP
  bot0<<<Bn*512/256,256,0,stream>>>(dense_x, bW0, bb0, P);
  gemm_bt<true><<<dim3(128,2),256,0,stream>>>(P,    wtB1, bb1, act1, Bn,256,512);
  gemm_bt<true><<<dim3(128,1),256,0,stream>>>(act1, wtB2, bb2, xb,   Bn,128,256);

  // gather + interaction -> R (in P)
  interact<<<Bn/4,256,0,stream>>>(xb, indices, emb, P);

  // top MLP
  gemm_bt<true><<<dim3(128,8),256,0,stream>>>(P,  wtT0, tb0, h1, Bn,1024,512);
  gemm_bt<true><<<dim3(128,8),256,0,stream>>>(h1, wtT1, tb1, h2, Bn,1024,1024);
  gemm_bt<true><<<dim3(128,4),256,0,stream>>>(h2, wtT2, tb2, P,  Bn,512,1024);
  finlayer<<<Bn/4,256,0,stream>>>(P, wtT3, tb3, out);
}

// Round 2
// 228.909 us; speedup vs baseline: 1.2252x; 1.2252x over previous
//
#include <hip/hip_runtime.h>

typedef __attribute__((ext_vector_type(8))) short short8;
typedef __attribute__((ext_vector_type(4))) float f32x4;
typedef __attribute__((ext_vector_type(16))) float f32x16;

#define B_ROWS 16384

__device__ __forceinline__ float bf2f(ushort u){ return __uint_as_float(((uint)u)<<16); }
__device__ __forceinline__ ushort f2bf(float f){
  uint u = __float_as_uint(f);
  u = u + 0x7FFFu + ((u>>16)&1u);
  return (ushort)(u>>16);
}
__device__ __forceinline__ void gload_lds16(const void* g, void* l){
  __builtin_amdgcn_global_load_lds((const __attribute__((address_space(1))) unsigned*)g,
                                   (__attribute__((address_space(3))) unsigned*)l, 16, 0, 0);
}

// ---------------- fused tiled transpose+convert: out[n*Kp+k] = bf16(in[k*N+n]) (0-pad k>=K)
struct TArgs { const float* in; ushort* out; int K, N, Kp; };
struct TArgs5 { TArgs a[5]; };

__global__ __launch_bounds__(256) void transp_tiled(TArgs5 args)
{
  TArgs t = args.a[blockIdx.z];
  int k0 = blockIdx.x*32, n0 = blockIdx.y*32;
  if (k0 >= t.Kp || n0 >= t.N) return;
  __shared__ float tile[32][33];
  const int c = threadIdx.x & 31, r8 = threadIdx.x >> 5;
  #pragma unroll
  for (int p=0;p<4;p++){
    int k = k0 + r8 + p*8;
    tile[r8+p*8][c] = (k < t.K) ? t.in[(size_t)k*t.N + n0 + c] : 0.f;
  }
  __syncthreads();
  #pragma unroll
  for (int p=0;p<4;p++){
    int n = n0 + r8 + p*8;
    t.out[(size_t)n*t.Kp + k0 + c] = f2bf(tile[c][r8+p*8]);
  }
}

// tW3 (512x1): contiguous copy-convert
__global__ __launch_bounds__(256) void transp_vec(const float* __restrict__ in, ushort* __restrict__ out, int n)
{
  int i = blockIdx.x*256 + threadIdx.x;
  if (i < n) out[i] = f2bf(in[i]);
}

// ---------------- bottom layer 0: (B,13) @ (13,512) + b, relu -> bf16
__global__ __launch_bounds__(256) void bot0(const float* __restrict__ x, const float* __restrict__ W,
                                            const float* __restrict__ bias, ushort* __restrict__ out)
{
  int i = blockIdx.x*256 + threadIdx.x;
  int b = i>>9, n = i&511;
  const float* xr = x + (size_t)b*13;
  float s = bias[n];
  #pragma unroll
  for (int k=0;k<13;k++) s += xr[k]*W[k*512+n];
  out[i] = f2bf(fmaxf(s,0.f));
}

// ---------------- 2-phase double-buffered bf16 GEMM (T3+T4 minimum recipe)
// C(M x N, row stride ldc) = relu(A(MxK) @ Bt(NxK)^T + bias)
template<bool RELU>
__global__ __launch_bounds__(256) void gemm_bt(const ushort* __restrict__ A,
    const ushort* __restrict__ Bt, const float* __restrict__ bias,
    ushort* __restrict__ C, int M, int N, int K, int ldc)
{
  constexpr int BM=128, BN=128, BK=64;
  __shared__ __align__(16) ushort lA[2][BM*BK];
  __shared__ __align__(16) ushort lB[2][BN*BK];
  const int tid = threadIdx.x;
  const int wave = tid>>6, lane = tid&63;
  const int bm = blockIdx.x*BM, bn = blockIdx.y*BN;
  const int wrr = (wave>>1)*64, wcc = (wave&1)*64;
  const int lr = lane&15, lg = lane>>4;
  const int nt = K>>6;
  const int ob0 = wave*4096 + lane*16;   // this thread's first byte seg

  f32x4 acc[4][4];
  #pragma unroll
  for (int m=0;m<4;m++)
    #pragma unroll
    for (int n=0;n<4;n++)
      #pragma unroll
      for (int j=0;j<4;j++) acc[m][n][j] = 0.f;

  auto stage = [&](int buf, int kt){
    #pragma unroll
    for (int c=0;c<4;c++){
      int o = ob0 + c*1024;
      int row = o>>7, colb = o&127;     // 128 B (64 bf16) per LDS row
      gload_lds16((const char*)A  + (((size_t)(bm+row)*K + (kt<<6))<<1) + colb, (char*)lA[buf] + o);
      gload_lds16((const char*)Bt + (((size_t)(bn+row)*K + (kt<<6))<<1) + colb, (char*)lB[buf] + o);
    }
  };

  stage(0, 0);
  int cur = 0;
  for (int t=0; t<nt; ++t){
    int nx = (t+1 < nt) ? t+1 : 0;      // last iter stages tile 0 (harmless, keeps count uniform)
    stage(cur^1, nx);
    // wait only for tile t's 8 loads (issued last iteration); keep the 8 new ones in flight
    asm volatile("s_waitcnt vmcnt(8)" ::: "memory");
    __builtin_amdgcn_s_barrier();
    asm volatile("" ::: "memory");
    #pragma unroll
    for (int kk=0;kk<BK;kk+=32){
      short8 af[4], bfr[4];
      const int lk = kk + lg*8;
      #pragma unroll
      for (int m=0;m<4;m++) af[m]  = *(const short8*)&lA[cur][(wrr+m*16+lr)*BK + lk];
      #pragma unroll
      for (int n=0;n<4;n++) bfr[n] = *(const short8*)&lB[cur][(wcc+n*16+lr)*BK + lk];
      #pragma unroll
      for (int m=0;m<4;m++)
        #pragma unroll
        for (int n=0;n<4;n++)
          acc[m][n] = __builtin_amdgcn_mfma_f32_16x16x32_bf16(af[m], bfr[n], acc[m][n], 0,0,0);
    }
    asm volatile("" ::: "memory");
    __builtin_amdgcn_s_barrier();
    cur ^= 1;
  }

  // epilogue: C/D layout col=lane&15, row=(lane>>4)*4+j
  #pragma unroll
  for (int n=0;n<4;n++){
    int col = bn + wcc + n*16 + lr;
    float bv = bias[col];
    #pragma unroll
    for (int m=0;m<4;m++){
      #pragma unroll
      for (int j=0;j<4;j++){
        int row = bm + wrr + m*16 + lg*4 + j;
        float v = acc[m][n][j] + bv;
        if (RELU) v = fmaxf(v,0.f);
        C[(size_t)row*ldc + col] = f2bf(v);
      }
    }
  }
}

// ---------------- embedding gather + pairwise interaction, in-place on R (B x 512 bf16)
// reads R[b][0:128]=x (written by bot2), writes R[b][128+p]=Z[LI,LJ], R[b][479:512]=0
__global__ __launch_bounds__(256) void interact(const int* __restrict__ idx,
    const float* __restrict__ emb, ushort* __restrict__ R)
{
  __shared__ __align__(16) ushort Tl[4][32][136];   // 27 rows used; 136 = 128 + pad
  const int w = threadIdx.x>>6, l = threadIdx.x&63;
  const int b = blockIdx.x*4 + w;
  ushort* Rrow = R + (size_t)b*512;

  // T row 0 = x (already bf16 in R)
  uint xv = ((const uint*)Rrow)[l];
  *(uint*)&Tl[w][0][2*l] = xv;

  int myidx = (l<26) ? idx[(size_t)l*B_ROWS + b] : 0;
  const int half = l>>5, lc = l&31;
  #pragma unroll
  for (int i=0;i<13;i++){
    const int row = 2*i + 1 + half;                 // 1..26
    int e = __shfl(myidx, row - 1);
    const float4* rp = (const float4*)(emb + ((size_t)(row-1)*50000 + (size_t)e)*128);
    float4 v = rp[lc];
    uint2 pk;
    pk.x = (uint)f2bf(v.x) | ((uint)f2bf(v.y)<<16);
    pk.y = (uint)f2bf(v.z) | ((uint)f2bf(v.w)<<16);
    *(uint2*)&Tl[w][row][4*lc] = pk;
  }
  __syncthreads();

  // Z = T @ T^T via 32x32x16 bf16 MFMA; A-frag == B-frag for symmetric product
  f32x16 acc;
  #pragma unroll
  for (int i=0;i<16;i++) acc[i] = 0.f;
  #pragma unroll
  for (int kk=0;kk<8;kk++){
    short8 fa = *(const short8*)((const char*)&Tl[w][0][0] + (size_t)(l&31)*272 + kk*32 + (l>>5)*16);
    acc = __builtin_amdgcn_mfma_f32_32x32x16_bf16(fa, fa, acc, 0,0,0);
  }

  const int c = l&31;
  #pragma unroll
  for (int j=0;j<16;j++){
    int r = (j&3) + 8*(j>>2) + 4*(l>>5);   // C/D: col=lane&31, row=(reg&3)+8*(reg>>2)+4*(lane>>5)
    if (c < r && r <= 26) Rrow[128 + r*(r-1)/2 + c] = f2bf(acc[j]);
  }
  if (l < 33) Rrow[479 + l] = 0;
}

// ---------------- final: sigmoid(h3 @ w + b), clip -> fp32 out
__global__ __launch_bounds__(256) void finlayer(const ushort* __restrict__ h3,
    const ushort* __restrict__ wt, const float* __restrict__ b3, float* __restrict__ out)
{
  int w = threadIdx.x>>6, l = threadIdx.x&63;
  int b = blockIdx.x*4 + w;
  short8 hv = *(const short8*)(h3 + (size_t)b*512 + l*8);
  short8 wv = *(const short8*)(wt + l*8);
  float s = 0.f;
  #pragma unroll
  for (int j=0;j<8;j++) s += bf2f((ushort)hv[j])*bf2f((ushort)wv[j]);
  #pragma unroll
  for (int off=32; off>0; off>>=1) s += __shfl_xor(s, off);
  if (l==0){
    float h = s + b3[0];
    float p = 1.f/(1.f + expf(-h));
    out[b] = fminf(fmaxf(p, 0.f), 1.f);
  }
}

extern "C" void kernel_launch(void* const* d_in, const int* in_sizes, int n_in,
                              void* d_out, int out_size, void* d_ws, size_t ws_size,
                              hipStream_t stream)
{
  const float* dense_x = (const float*)d_in[0];
  const int*   indices = (const int*)d_in[1];
  const float* emb     = (const float*)d_in[2];
  const float* bW0 = (const float*)d_in[3];  const float* bb0 = (const float*)d_in[4];
  const float* bW1 = (const float*)d_in[5];  const float* bb1 = (const float*)d_in[6];
  const float* bW2 = (const float*)d_in[7];  const float* bb2 = (const float*)d_in[8];
  const float* tW0 = (const float*)d_in[9];  const float* tb0 = (const float*)d_in[10];
  const float* tW1 = (const float*)d_in[11]; const float* tb1 = (const float*)d_in[12];
  const float* tW2 = (const float*)d_in[13]; const float* tb2 = (const float*)d_in[14];
  const float* tW3 = (const float*)d_in[15]; const float* tb3 = (const float*)d_in[16];
  float* out = (float*)d_out;
  const int Bn = B_ROWS;

  char* ws = (char*)d_ws;
  size_t o = 0;
  auto alloc = [&](size_t bytes)->char*{ char* r = ws + o; o += (bytes + 255) & ~(size_t)255; return r; };
  ushort* wtB1 = (ushort*)alloc(256*512*2);         // bot_W1^T  (256 x 512)
  ushort* wtB2 = (ushort*)alloc(128*256*2);         // bot_W2^T  (128 x 256)
  ushort* wtT0 = (ushort*)alloc(1024*512*2);        // top_W0^T  (1024 x 512, K 479->512)
  ushort* wtT1 = (ushort*)alloc((size_t)1024*1024*2);
  ushort* wtT2 = (ushort*)alloc(512*1024*2);
  ushort* wtT3 = (ushort*)alloc(512*2);
  ushort* P    = (ushort*)alloc((size_t)Bn*512*2);  // act0 -> x+R -> h3 (reused)
  ushort* act1 = (ushort*)alloc((size_t)Bn*256*2);
  ushort* h1   = (ushort*)alloc((size_t)Bn*1024*2);
  ushort* h2   = (ushort*)alloc((size_t)Bn*1024*2);
  (void)ws_size; (void)in_sizes; (void)n_in; (void)out_size;

  // fused weight prep (coalesced tiled transposes)
  TArgs5 ta;
  ta.a[0] = { bW1, wtB1, 512 , 256 , 512  };
  ta.a[1] = { bW2, wtB2, 256 , 128 , 256  };
  ta.a[2] = { tW0, wtT0, 479 , 1024, 512  };
  ta.a[3] = { tW1, wtT1, 1024, 1024, 1024 };
  ta.a[4] = { tW2, wtT2, 1024, 512 , 1024 };
  transp_tiled<<<dim3(32,32,5),256,0,stream>>>(ta);
  transp_vec<<<2,256,0,stream>>>(tW3, wtT3, 512);

  // bottom MLP (bot2 writes x directly into R rows, ldc=512)
  bot0<<<Bn*512/256,256,0,stream>>>(dense_x, bW0, bb0, P);
  gemm_bt<true><<<dim3(128,2),256,0,stream>>>(P,    wtB1, bb1, act1, Bn,256,512, 256);
  gemm_bt<true><<<dim3(128,1),256,0,stream>>>(act1, wtB2, bb2, P,    Bn,128,256, 512);

  // gather + interaction in place on R (= P)
  interact<<<Bn/4,256,0,stream>>>(indices, emb, P);

  // top MLP
  gemm_bt<true><<<dim3(128,8),256,0,stream>>>(P,  wtT0, tb0, h1, Bn,1024,512 , 1024);
  gemm_bt<true><<<dim3(128,8),256,0,stream>>>(h1, wtT1, tb1, h2, Bn,1024,1024, 1024);
  gemm_bt<true><<<dim3(128,4),256,0,stream>>>(h2, wtT2, tb2, P,  Bn,512 ,1024, 512);
  finlayer<<<Bn/4,256,0,stream>>>(P, wtT3, tb3, out);
}

// Round 3
// 201.563 us; speedup vs baseline: 1.3915x; 1.1357x over previous
//
#include <hip/hip_runtime.h>

typedef __attribute__((ext_vector_type(8))) short short8;
typedef __attribute__((ext_vector_type(4))) float f32x4;
typedef __attribute__((ext_vector_type(16))) float f32x16;

#define B_ROWS 16384

__device__ __forceinline__ float bf2f(ushort u){ return __uint_as_float(((uint)u)<<16); }
__device__ __forceinline__ ushort f2bf(float f){
  uint u = __float_as_uint(f);
  u = u + 0x7FFFu + ((u>>16)&1u);
  return (ushort)(u>>16);
}
__device__ __forceinline__ void gload_lds16(const void* g, void* l){
  __builtin_amdgcn_global_load_lds((const __attribute__((address_space(1))) unsigned*)g,
                                   (__attribute__((address_space(3))) unsigned*)l, 16, 0, 0);
}

// ---------------- fused tiled transpose+convert: out[n*Kp+k] = bf16(in[k*N+n]) (0-pad k>=K)
struct TArgs { const float* in; ushort* out; int K, N, Kp; };
struct TArgs5 { TArgs a[5]; };

__global__ __launch_bounds__(256) void transp_tiled(TArgs5 args)
{
  TArgs t = args.a[blockIdx.z];
  int k0 = blockIdx.x*32, n0 = blockIdx.y*32;
  if (k0 >= t.Kp || n0 >= t.N) return;
  __shared__ float tile[32][33];
  const int c = threadIdx.x & 31, r8 = threadIdx.x >> 5;
  #pragma unroll
  for (int p=0;p<4;p++){
    int k = k0 + r8 + p*8;
    tile[r8+p*8][c] = (k < t.K) ? t.in[(size_t)k*t.N + n0 + c] : 0.f;
  }
  __syncthreads();
  #pragma unroll
  for (int p=0;p<4;p++){
    int n = n0 + r8 + p*8;
    t.out[(size_t)n*t.Kp + k0 + c] = f2bf(tile[c][r8+p*8]);
  }
}

__global__ __launch_bounds__(256) void transp_vec(const float* __restrict__ in, ushort* __restrict__ out, int n)
{
  int i = blockIdx.x*256 + threadIdx.x;
  if (i < n) out[i] = f2bf(in[i]);
}

// ---------------- bottom layer 0: (B,13) @ (13,512) + b, relu -> bf16
__global__ __launch_bounds__(256) void bot0(const float* __restrict__ x, const float* __restrict__ W,
                                            const float* __restrict__ bias, ushort* __restrict__ out)
{
  int i = blockIdx.x*256 + threadIdx.x;
  int b = i>>9, n = i&511;
  const float* xr = x + (size_t)b*13;
  float s = bias[n];
  #pragma unroll
  for (int k=0;k<13;k++) s += xr[k]*W[k*512+n];
  out[i] = f2bf(fmaxf(s,0.f));
}

// ---------------- 128^2 2-phase GEMM (kept for small-N bottom layers)
template<bool RELU>
__global__ __launch_bounds__(256) void gemm_bt(const ushort* __restrict__ A,
    const ushort* __restrict__ Bt, const float* __restrict__ bias,
    ushort* __restrict__ C, int M, int N, int K, int ldc)
{
  constexpr int BK=64;
  __shared__ __align__(16) ushort lA[2][128*BK];
  __shared__ __align__(16) ushort lB[2][128*BK];
  const int tid = threadIdx.x;
  const int wave = tid>>6, lane = tid&63;
  const int bm = blockIdx.x*128, bn = blockIdx.y*128;
  const int wrr = (wave>>1)*64, wcc = (wave&1)*64;
  const int lr = lane&15, lg = lane>>4;
  const int nt = K>>6;
  const int ob0 = wave*4096 + lane*16;

  f32x4 acc[4][4];
  #pragma unroll
  for (int m=0;m<4;m++)
    #pragma unroll
    for (int n=0;n<4;n++)
      #pragma unroll
      for (int j=0;j<4;j++) acc[m][n][j] = 0.f;

  auto stage = [&](int buf, int kt){
    #pragma unroll
    for (int c=0;c<4;c++){
      int o = ob0 + c*1024;
      int row = o>>7, colb = o&127;
      gload_lds16((const char*)A  + (((size_t)(bm+row)*K + (kt<<6))<<1) + colb, (char*)lA[buf] + o);
      gload_lds16((const char*)Bt + (((size_t)(bn+row)*K + (kt<<6))<<1) + colb, (char*)lB[buf] + o);
    }
  };

  stage(0, 0);
  int cur = 0;
  for (int t=0; t<nt; ++t){
    int nx = (t+1 < nt) ? t+1 : 0;
    stage(cur^1, nx);
    asm volatile("s_waitcnt vmcnt(8)" ::: "memory");
    __builtin_amdgcn_s_barrier();
    asm volatile("" ::: "memory");
    #pragma unroll
    for (int kk=0;kk<BK;kk+=32){
      short8 af[4], bfr[4];
      const int lk = kk + lg*8;
      #pragma unroll
      for (int m=0;m<4;m++) af[m]  = *(const short8*)&lA[cur][(wrr+m*16+lr)*BK + lk];
      #pragma unroll
      for (int n=0;n<4;n++) bfr[n] = *(const short8*)&lB[cur][(wcc+n*16+lr)*BK + lk];
      #pragma unroll
      for (int m=0;m<4;m++)
        #pragma unroll
        for (int n=0;n<4;n++)
          acc[m][n] = __builtin_amdgcn_mfma_f32_16x16x32_bf16(af[m], bfr[n], acc[m][n], 0,0,0);
    }
    asm volatile("" ::: "memory");
    __builtin_amdgcn_s_barrier();
    cur ^= 1;
  }

  #pragma unroll
  for (int n=0;n<4;n++){
    int col = bn + wcc + n*16 + lr;
    float bv = bias[col];
    #pragma unroll
    for (int m=0;m<4;m++){
      #pragma unroll
      for (int j=0;j<4;j++){
        int row = bm + wrr + m*16 + lg*4 + j;
        float v = acc[m][n][j] + bv;
        if (RELU) v = fmaxf(v,0.f);
        C[(size_t)row*ldc + col] = f2bf(v);
      }
    }
  }
}

// ---------------- 256xBN deep-pipelined GEMM, 8 phases / 2 K-tiles, counted vmcnt, swizzled LDS
// C = relu(A(MxK) @ Bt(NxK)^T + bias). Requires M%256==0, N%BN==0, K%128==0.
// LDS half-regions per buffer: A_klo, A_khi (16KiB each), B_klo, B_khi (BN*64 B each).
// Stage ledger (iter i, E=2i buf0, O=2i+1 buf1), checkpoints (vmcnt, never 0) end of even phases:
//  p1(E,k0,mlo): stage A_khi(O)    p2(E,k0,mhi): B_khi(O)   [ckpt]
//  p3(E,k1,mlo): stage A_klo(E+2)  p4(E,k1,mhi): B_klo(E+2) [ckpt]
//  p5(O,k0,mlo): stage A_khi(E+2)  p6(O,k0,mhi): B_khi(E+2) [ckpt]
//  p7(O,k1,mlo): stage A_klo(O+2)  p8(O,k1,mhi): B_klo(O+2) [ckpt]
// Every stage issues >=1 barrier after its slot's last read; every read >=2 checkpoints after issue.
template<int BN>
__global__ __launch_bounds__(512, 2) void gemm256(const ushort* __restrict__ A,
    const ushort* __restrict__ Bt, const float* __restrict__ bias,
    ushort* __restrict__ C, int K, int ldc)
{
  constexpr int  NF = BN/64;              // B fragments per wave
  constexpr int  LB = BN/128;             // loads/thread per B half-stage
  constexpr uint BR = (uint)BN*32u;       // ushorts per B half-region
  constexpr uint BUFSZ = 16384u + 2u*BR;  // ushorts per buffer
  __shared__ __align__(16) ushort lds[2*BUFSZ];

  const int tid = threadIdx.x;
  const int wave = tid>>6, lane = tid&63;
  const uint wm = (uint)(wave>>2), wn = (uint)(wave&3);   // 2 x 4 wave grid
  const uint lr = (uint)(lane&15), lg = (uint)((lane>>4)&3);
  const int bm = blockIdx.x*256, bn = blockIdx.y*BN;
  const int nt = K>>6, niter = nt>>1;

  f32x4 acc[8][NF];
  #pragma unroll
  for (int m=0;m<8;m++)
    #pragma unroll
    for (int n=0;n<NF;n++)
      #pragma unroll
      for (int j=0;j<4;j++) acc[m][n][j] = 0.f;

  short8 af[4];
  short8 bf[NF];

#define STAGE(MAT, KH, TILE, SBUF) do{                                          \
    int kt_ = (TILE);                                                           \
    int ktc_ = (kt_ < nt) ? kt_ : 0;   /* tail: slot is dead, data unused */    \
    const ushort* gb_ = (MAT) ? Bt : A;                                         \
    const uint ro_ = (MAT) ? (uint)bn : (uint)bm;                               \
    const uint rb_ = (uint)(SBUF)*BUFSZ + ((MAT) ? (16384u + (uint)(KH)*BR)     \
                                                 : ((uint)(KH)*8192u));         \
    const int nl_ = (MAT) ? LB : 2;                                             \
    _Pragma("unroll")                                                           \
    for (int j_=0; j_<nl_; ++j_){                                               \
      uint lin_ = (uint)tid*16u + (uint)j_*8192u;                               \
      uint src_ = lin_ ^ (((lin_>>7)&3u)<<4);                                   \
      uint row_ = src_>>6, colb_ = src_&63u;                                    \
      const char* g_ = (const char*)gb_ +                                       \
        (((size_t)(ro_+row_)*(size_t)K + (size_t)ktc_*64 + (KH)*32)<<1) + colb_;\
      gload_lds16(g_, (char*)lds + (size_t)rb_*2 + lin_);                       \
    }                                                                           \
  }while(0)

#define PHASE(CBUF, KKH, MH, BLOAD, SMAT, SKH, STILE, SBUF, CKPT) do{           \
    const uint ab_ = (uint)(CBUF)*BUFSZ + (uint)(KKH)*8192u;                    \
    _Pragma("unroll")                                                           \
    for (int mf_=0; mf_<4; ++mf_){                                              \
      uint r_ = wm*128u + ((uint)(MH)*4u+(uint)mf_)*16u + lr;                   \
      uint l_ = r_*64u + lg*16u;                                                \
      af[mf_] = *(const short8*)((const char*)lds + (size_t)ab_*2               \
                                 + (l_ ^ (((l_>>7)&3u)<<4)));                   \
    }                                                                           \
    if (BLOAD){                                                                 \
      const uint bb_ = (uint)(CBUF)*BUFSZ + 16384u + (uint)(KKH)*BR;            \
      _Pragma("unroll")                                                         \
      for (int nf_=0; nf_<NF; ++nf_){                                           \
        uint r_ = wn*(uint)(BN/4) + (uint)nf_*16u + lr;                         \
        uint l_ = r_*64u + lg*16u;                                              \
        bf[nf_] = *(const short8*)((const char*)lds + (size_t)bb_*2             \
                                   + (l_ ^ (((l_>>7)&3u)<<4)));                 \
      }                                                                         \
    }                                                                           \
    STAGE(SMAT, SKH, STILE, SBUF);                                              \
    asm volatile("" ::: "memory");                                              \
    __builtin_amdgcn_s_barrier();                                               \
    asm volatile("" ::: "memory");                                              \
    __builtin_amdgcn_s_setprio(1);                                              \
    _Pragma("unroll")                                                           \
    for (int mf_=0; mf_<4; ++mf_)                                               \
      _Pragma("unroll")                                                         \
      for (int nf_=0; nf_<NF; ++nf_)                                            \
        acc[(MH)*4+mf_][nf_] = __builtin_amdgcn_mfma_f32_16x16x32_bf16(         \
            af[mf_], bf[nf_], acc[(MH)*4+mf_][nf_], 0,0,0);                     \
    __builtin_amdgcn_s_setprio(0);                                              \
    if (CKPT){                                                                  \
      if constexpr (LB==2) asm volatile("s_waitcnt vmcnt(4)" ::: "memory");     \
      else                 asm volatile("s_waitcnt vmcnt(3)" ::: "memory");     \
    }                                                                           \
    asm volatile("" ::: "memory");                                              \
    __builtin_amdgcn_s_barrier();                                               \
  }while(0)

  // prologue: tile0 (all 4 halves) + tile1 klo; counted wait leaves tile1-klo in flight
  STAGE(0,0,0,0); STAGE(1,0,0,0); STAGE(0,1,0,0); STAGE(1,1,0,0);
  STAGE(0,0,1,1); STAGE(1,0,1,1);
  if constexpr (LB==2) asm volatile("s_waitcnt vmcnt(4)" ::: "memory");
  else                 asm volatile("s_waitcnt vmcnt(3)" ::: "memory");
  asm volatile("" ::: "memory");
  __builtin_amdgcn_s_barrier();

  for (int i=0; i<niter; ++i){
    const int O  = 2*i+1;
    const int E2 = 2*i+2;
    const int O2 = 2*i+3;
    PHASE(0,0,0,true , 0,1,O ,1, false);
    PHASE(0,0,1,false, 1,1,O ,1, true );
    PHASE(0,1,0,true , 0,0,E2,0, false);
    PHASE(0,1,1,false, 1,0,E2,0, true );
    PHASE(1,0,0,true , 0,1,E2,0, false);
    PHASE(1,0,1,false, 1,1,E2,0, true );
    PHASE(1,1,0,true , 0,0,O2,1, false);
    PHASE(1,1,1,false, 1,0,O2,1, true );
  }
#undef PHASE
#undef STAGE

  #pragma unroll
  for (int nf=0; nf<NF; ++nf){
    int col = bn + (int)wn*(BN/4) + nf*16 + (int)lr;
    float bv = bias[col];
    #pragma unroll
    for (int mf=0; mf<8; ++mf){
      #pragma unroll
      for (int jj=0; jj<4; ++jj){
        int row = bm + (int)wm*128 + mf*16 + (int)lg*4 + jj;
        float v = acc[mf][nf][jj] + bv;
        C[(size_t)row*ldc + col] = f2bf(fmaxf(v, 0.f));
      }
    }
  }
}

// ---------------- embedding gather + pairwise interaction, in-place on R (B x 512 bf16)
__global__ __launch_bounds__(256) void interact(const int* __restrict__ idx,
    const float* __restrict__ emb, ushort* __restrict__ R)
{
  __shared__ __align__(16) ushort Tl[4][32][136];
  const int w = threadIdx.x>>6, l = threadIdx.x&63;
  const int b = blockIdx.x*4 + w;
  ushort* Rrow = R + (size_t)b*512;

  uint xv = ((const uint*)Rrow)[l];
  *(uint*)&Tl[w][0][2*l] = xv;

  int myidx = (l<26) ? idx[(size_t)l*B_ROWS + b] : 0;
  const int half = l>>5, lc = l&31;
  #pragma unroll
  for (int i=0;i<13;i++){
    const int row = 2*i + 1 + half;
    int e = __shfl(myidx, row - 1);
    const float4* rp = (const float4*)(emb + ((size_t)(row-1)*50000 + (size_t)e)*128);
    float4 v = rp[lc];
    uint2 pk;
    pk.x = (uint)f2bf(v.x) | ((uint)f2bf(v.y)<<16);
    pk.y = (uint)f2bf(v.z) | ((uint)f2bf(v.w)<<16);
    *(uint2*)&Tl[w][row][4*lc] = pk;
  }
  __syncthreads();

  f32x16 acc;
  #pragma unroll
  for (int i=0;i<16;i++) acc[i] = 0.f;
  #pragma unroll
  for (int kk=0;kk<8;kk++){
    short8 fa = *(const short8*)((const char*)&Tl[w][0][0] + (size_t)(l&31)*272 + kk*32 + (l>>5)*16);
    acc = __builtin_amdgcn_mfma_f32_32x32x16_bf16(fa, fa, acc, 0,0,0);
  }

  const int c = l&31;
  #pragma unroll
  for (int j=0;j<16;j++){
    int r = (j&3) + 8*(j>>2) + 4*(l>>5);
    if (c < r && r <= 26) Rrow[128 + r*(r-1)/2 + c] = f2bf(acc[j]);
  }
  if (l < 33) Rrow[479 + l] = 0;
}

// ---------------- final: sigmoid(h3 @ w + b), clip -> fp32 out
__global__ __launch_bounds__(256) void finlayer(const ushort* __restrict__ h3,
    const ushort* __restrict__ wt, const float* __restrict__ b3, float* __restrict__ out)
{
  int w = threadIdx.x>>6, l = threadIdx.x&63;
  int b = blockIdx.x*4 + w;
  short8 hv = *(const short8*)(h3 + (size_t)b*512 + l*8);
  short8 wv = *(const short8*)(wt + l*8);
  float s = 0.f;
  #pragma unroll
  for (int j=0;j<8;j++) s += bf2f((ushort)hv[j])*bf2f((ushort)wv[j]);
  #pragma unroll
  for (int off=32; off>0; off>>=1) s += __shfl_xor(s, off);
  if (l==0){
    float h = s + b3[0];
    float p = 1.f/(1.f + expf(-h));
    out[b] = fminf(fmaxf(p, 0.f), 1.f);
  }
}

extern "C" void kernel_launch(void* const* d_in, const int* in_sizes, int n_in,
                              void* d_out, int out_size, void* d_ws, size_t ws_size,
                              hipStream_t stream)
{
  const float* dense_x = (const float*)d_in[0];
  const int*   indices = (const int*)d_in[1];
  const float* emb     = (const float*)d_in[2];
  const float* bW0 = (const float*)d_in[3];  const float* bb0 = (const float*)d_in[4];
  const float* bW1 = (const float*)d_in[5];  const float* bb1 = (const float*)d_in[6];
  const float* bW2 = (const float*)d_in[7];  const float* bb2 = (const float*)d_in[8];
  const float* tW0 = (const float*)d_in[9];  const float* tb0 = (const float*)d_in[10];
  const float* tW1 = (const float*)d_in[11]; const float* tb1 = (const float*)d_in[12];
  const float* tW2 = (const float*)d_in[13]; const float* tb2 = (const float*)d_in[14];
  const float* tW3 = (const float*)d_in[15]; const float* tb3 = (const float*)d_in[16];
  float* out = (float*)d_out;
  const int Bn = B_ROWS;

  char* ws = (char*)d_ws;
  size_t o = 0;
  auto alloc = [&](size_t bytes)->char*{ char* r = ws + o; o += (bytes + 255) & ~(size_t)255; return r; };
  ushort* wtB1 = (ushort*)alloc(256*512*2);
  ushort* wtB2 = (ushort*)alloc(128*256*2);
  ushort* wtT0 = (ushort*)alloc(1024*512*2);
  ushort* wtT1 = (ushort*)alloc((size_t)1024*1024*2);
  ushort* wtT2 = (ushort*)alloc(512*1024*2);
  ushort* wtT3 = (ushort*)alloc(512*2);
  ushort* P    = (ushort*)alloc((size_t)Bn*512*2);
  ushort* act1 = (ushort*)alloc((size_t)Bn*256*2);
  ushort* h1   = (ushort*)alloc((size_t)Bn*1024*2);
  ushort* h2   = (ushort*)alloc((size_t)Bn*1024*2);
  (void)ws_size; (void)in_sizes; (void)n_in; (void)out_size;

  TArgs5 ta;
  ta.a[0] = { bW1, wtB1, 512 , 256 , 512  };
  ta.a[1] = { bW2, wtB2, 256 , 128 , 256  };
  ta.a[2] = { tW0, wtT0, 479 , 1024, 512  };
  ta.a[3] = { tW1, wtT1, 1024, 1024, 1024 };
  ta.a[4] = { tW2, wtT2, 1024, 512 , 1024 };
  transp_tiled<<<dim3(32,32,5),256,0,stream>>>(ta);
  transp_vec<<<2,256,0,stream>>>(tW3, wtT3, 512);

  // bottom MLP (bot2 writes x directly into R rows, ldc=512)
  bot0<<<Bn*512/256,256,0,stream>>>(dense_x, bW0, bb0, P);
  gemm_bt<true><<<dim3(128,2),256,0,stream>>>(P,    wtB1, bb1, act1, Bn,256,512, 256);
  gemm_bt<true><<<dim3(128,1),256,0,stream>>>(act1, wtB2, bb2, P,    Bn,128,256, 512);

  // gather + interaction in place on R (= P)
  interact<<<Bn/4,256,0,stream>>>(indices, emb, P);

  // top MLP: deep-pipelined 256-tile GEMMs
  gemm256<256><<<dim3(64,4),512,0,stream>>>(P,  wtT0, tb0, h1, 512 , 1024);
  gemm256<256><<<dim3(64,4),512,0,stream>>>(h1, wtT1, tb1, h2, 1024, 1024);
  gemm256<128><<<dim3(64,4),512,0,stream>>>(h2, wtT2, tb2, P,  1024, 512);
  finlayer<<<Bn/4,256,0,stream>>>(P, wtT3, tb3, out);
}

// Round 4
// 196.972 us; speedup vs baseline: 1.4239x; 1.0233x over previous
//
#include <hip/hip_runtime.h>

typedef __attribute__((ext_vector_type(8))) short short8;
typedef __attribute__((ext_vector_type(4))) float f32x4;
typedef __attribute__((ext_vector_type(16))) float f32x16;

#define B_ROWS 16384

__device__ __forceinline__ float bf2f(ushort u){ return __uint_as_float(((uint)u)<<16); }
__device__ __forceinline__ ushort f2bf(float f){
  uint u = __float_as_uint(f);
  u = u + 0x7FFFu + ((u>>16)&1u);
  return (ushort)(u>>16);
}
__device__ __forceinline__ void gload_lds16(const void* g, void* l){
  __builtin_amdgcn_global_load_lds((const __attribute__((address_space(1))) unsigned*)g,
                                   (__attribute__((address_space(3))) unsigned*)l, 16, 0, 0);
}

// ---------------- fused tiled transpose+convert: out[n*Kp+k] = bf16(in[k*N+n]) (0-pad k>=K)
// slice with K==0: plain copy-convert of N elements (block 0,0 only)
struct TArgs { const float* in; ushort* out; int K, N, Kp; };
struct TArgs6 { TArgs a[6]; };

__global__ __launch_bounds__(256) void transp_tiled(TArgs6 args)
{
  TArgs t = args.a[blockIdx.z];
  if (t.K == 0){
    if (blockIdx.x==0 && blockIdx.y==0)
      for (int i = threadIdx.x; i < t.N; i += 256) t.out[i] = f2bf(t.in[i]);
    return;
  }
  int k0 = blockIdx.x*32, n0 = blockIdx.y*32;
  if (k0 >= t.Kp || n0 >= t.N) return;
  __shared__ float tile[32][33];
  const int c = threadIdx.x & 31, r8 = threadIdx.x >> 5;
  #pragma unroll
  for (int p=0;p<4;p++){
    int k = k0 + r8 + p*8;
    tile[r8+p*8][c] = (k < t.K) ? t.in[(size_t)k*t.N + n0 + c] : 0.f;
  }
  __syncthreads();
  #pragma unroll
  for (int p=0;p<4;p++){
    int n = n0 + r8 + p*8;
    t.out[(size_t)n*t.Kp + k0 + c] = f2bf(tile[c][r8+p*8]);
  }
}

// ---------------- bottom layer 0: (B,13) @ (13,512) + b, relu -> bf16
__global__ __launch_bounds__(256) void bot0(const float* __restrict__ x, const float* __restrict__ W,
                                            const float* __restrict__ bias, ushort* __restrict__ out)
{
  int i = blockIdx.x*256 + threadIdx.x;
  int b = i>>9, n = i&511;
  const float* xr = x + (size_t)b*13;
  float s = bias[n];
  #pragma unroll
  for (int k=0;k<13;k++) s += xr[k]*W[k*512+n];
  out[i] = f2bf(fmaxf(s,0.f));
}

// ---------------- BMx128 2-phase GEMM (bottom layers). BM = TM*32.
template<int TM, bool RELU>
__global__ __launch_bounds__(256) void gemm_bt(const ushort* __restrict__ A,
    const ushort* __restrict__ Bt, const float* __restrict__ bias,
    ushort* __restrict__ C, int M, int N, int K, int ldc)
{
  constexpr int BM = TM*32;
  __shared__ __align__(16) ushort lA[2][BM*64];
  __shared__ __align__(16) ushort lB[2][128*64];
  const int tid = threadIdx.x;
  const int wave = tid>>6, lane = tid&63;
  const int bm = blockIdx.x*BM, bn = blockIdx.y*128;
  const int wrr = (wave>>1)*(BM/2), wcc = (wave&1)*64;
  const int lr = lane&15, lg = lane>>4;
  const int nt = K>>6;
  const int obA = wave*(TM*1024) + lane*16;
  const int obB = wave*4096 + lane*16;

  f32x4 acc[TM][4];
  #pragma unroll
  for (int m=0;m<TM;m++)
    #pragma unroll
    for (int n=0;n<4;n++)
      #pragma unroll
      for (int j=0;j<4;j++) acc[m][n][j] = 0.f;

  auto stage = [&](int buf, int kt){
    #pragma unroll
    for (int c=0;c<TM;c++){
      int o = obA + c*1024;
      int row = o>>7, colb = o&127;
      gload_lds16((const char*)A  + (((size_t)(bm+row)*K + (kt<<6))<<1) + colb, (char*)lA[buf] + o);
    }
    #pragma unroll
    for (int c=0;c<4;c++){
      int o = obB + c*1024;
      int row = o>>7, colb = o&127;
      gload_lds16((const char*)Bt + (((size_t)(bn+row)*K + (kt<<6))<<1) + colb, (char*)lB[buf] + o);
    }
  };

  stage(0, 0);
  int cur = 0;
  for (int t=0; t<nt; ++t){
    int nx = (t+1 < nt) ? t+1 : 0;
    stage(cur^1, nx);
    if constexpr (TM==4) asm volatile("s_waitcnt vmcnt(8)" ::: "memory");
    else                 asm volatile("s_waitcnt vmcnt(6)" ::: "memory");
    __builtin_amdgcn_s_barrier();
    asm volatile("" ::: "memory");
    #pragma unroll
    for (int kk=0;kk<64;kk+=32){
      short8 af[TM], bfr[4];
      const int lk = kk + lg*8;
      #pragma unroll
      for (int m=0;m<TM;m++) af[m]  = *(const short8*)&lA[cur][(wrr+m*16+lr)*64 + lk];
      #pragma unroll
      for (int n=0;n<4;n++) bfr[n] = *(const short8*)&lB[cur][(wcc+n*16+lr)*64 + lk];
      #pragma unroll
      for (int m=0;m<TM;m++)
        #pragma unroll
        for (int n=0;n<4;n++)
          acc[m][n] = __builtin_amdgcn_mfma_f32_16x16x32_bf16(af[m], bfr[n], acc[m][n], 0,0,0);
    }
    asm volatile("" ::: "memory");
    __builtin_amdgcn_s_barrier();
    cur ^= 1;
  }

  #pragma unroll
  for (int n=0;n<4;n++){
    int col = bn + wcc + n*16 + lr;
    float bv = bias[col];
    #pragma unroll
    for (int m=0;m<TM;m++){
      #pragma unroll
      for (int j=0;j<4;j++){
        int row = bm + wrr + m*16 + lg*4 + j;
        float v = acc[m][n][j] + bv;
        if (RELU) v = fmaxf(v,0.f);
        C[(size_t)row*ldc + col] = f2bf(v);
      }
    }
  }
}

// ---------------- 256xBN deep-pipelined GEMM, 8 phases / 2 K-tiles, counted vmcnt, swizzled LDS
// 32x32x16 MFMA. C = relu(A(MxK) @ Bt(NxK)^T + bias). M%256==0, N%BN==0, K%128==0.
// LDS half-regions per buffer: A_klo, A_khi (16KiB), B_klo, B_khi (BN*64 B).
// Stage ledger (iter i, E=2i buf0, O=2i+1 buf1), ckpt (counted vmcnt) end of even phases:
//  p1(E,k0,mlo): A_khi(O)    p2(E,k0,mhi): B_khi(O)   [ckpt]
//  p3(E,k1,mlo): A_klo(E+2)  p4(E,k1,mhi): B_klo(E+2) [ckpt]
//  p5(O,k0,mlo): A_khi(E+2)  p6(O,k0,mhi): B_khi(E+2) [ckpt]
//  p7(O,k1,mlo): A_klo(O+2)  p8(O,k1,mhi): B_klo(O+2) [ckpt]
template<int BN>
__global__ __launch_bounds__(512, 2) void gemm256(const ushort* __restrict__ A,
    const ushort* __restrict__ Bt, const float* __restrict__ bias,
    ushort* __restrict__ C, int K, int ldc)
{
  constexpr int  NF = BN/128;             // 32-col B fragments per wave (wave cols = BN/4)
  constexpr int  LB = BN/128;             // loads/thread per B half-stage
  constexpr uint BR = (uint)BN*32u;       // ushorts per B half-region
  constexpr uint BUFSZ = 16384u + 2u*BR;  // ushorts per buffer
  __shared__ __align__(16) ushort lds[2*BUFSZ];

  const int tid = threadIdx.x;
  const int wave = tid>>6, lane = tid&63;
  const uint wm = (uint)(wave>>2), wn = (uint)(wave&3);   // 2 x 4 wave grid
  const uint lc = (uint)(lane&31), hi = (uint)(lane>>5);
  const int bm = blockIdx.x*256, bn = blockIdx.y*BN;
  const int nt = K>>6, niter = nt>>1;

  f32x16 acc[4][NF];
  #pragma unroll
  for (int m=0;m<4;m++)
    #pragma unroll
    for (int n=0;n<NF;n++)
      #pragma unroll
      for (int j=0;j<16;j++) acc[m][n][j] = 0.f;

  short8 bfr[2][NF];   // persists MH=0 -> MH=1 phases

#define STAGE(MAT, KH, TILE, SBUF) do{                                          \
    int kt_ = (TILE);                                                           \
    int ktc_ = (kt_ < nt) ? kt_ : 0;   /* tail: slot is dead, data unused */    \
    const ushort* gb_ = (MAT) ? Bt : A;                                         \
    const uint ro_ = (MAT) ? (uint)bn : (uint)bm;                               \
    const uint rb_ = (uint)(SBUF)*BUFSZ + ((MAT) ? (16384u + (uint)(KH)*BR)     \
                                                 : ((uint)(KH)*8192u));         \
    const int nl_ = (MAT) ? LB : 2;                                             \
    _Pragma("unroll")                                                           \
    for (int j_=0; j_<nl_; ++j_){                                               \
      uint lin_ = (uint)tid*16u + (uint)j_*8192u;                               \
      uint src_ = lin_ ^ (((lin_>>7)&3u)<<4);                                   \
      uint row_ = src_>>6, colb_ = src_&63u;                                    \
      const char* g_ = (const char*)gb_ +                                       \
        (((size_t)(ro_+row_)*(size_t)K + (size_t)ktc_*64 + (KH)*32)<<1) + colb_;\
      gload_lds16(g_, (char*)lds + (size_t)rb_*2 + lin_);                       \
    }                                                                           \
  }while(0)

#define PHASE(CBUF, KKH, MH, BLOAD, SMAT, SKH, STILE, SBUF, CKPT) do{           \
    const uint ab_ = (uint)(CBUF)*BUFSZ + (uint)(KKH)*8192u;                    \
    short8 af_[2][2];                                                           \
    _Pragma("unroll")                                                           \
    for (int mfl_=0; mfl_<2; ++mfl_){                                           \
      uint r_ = wm*128u + ((uint)(MH)*2u+(uint)mfl_)*32u + lc;                  \
      _Pragma("unroll")                                                         \
      for (int k2_=0; k2_<2; ++k2_){                                            \
        uint l_ = r_*64u + hi*16u + (uint)k2_*32u;                              \
        af_[mfl_][k2_] = *(const short8*)((const char*)lds + (size_t)ab_*2      \
                                   + (l_ ^ (((l_>>7)&3u)<<4)));                 \
      }                                                                         \
    }                                                                           \
    if (BLOAD){                                                                 \
      const uint bb_ = (uint)(CBUF)*BUFSZ + 16384u + (uint)(KKH)*BR;            \
      _Pragma("unroll")                                                         \
      for (int nf_=0; nf_<NF; ++nf_){                                           \
        uint r_ = wn*(uint)(BN/4) + (uint)nf_*32u + lc;                         \
        _Pragma("unroll")                                                       \
        for (int k2_=0; k2_<2; ++k2_){                                          \
          uint l_ = r_*64u + hi*16u + (uint)k2_*32u;                            \
          bfr[k2_][nf_] = *(const short8*)((const char*)lds + (size_t)bb_*2     \
                                     + (l_ ^ (((l_>>7)&3u)<<4)));               \
        }                                                                       \
      }                                                                         \
    }                                                                           \
    STAGE(SMAT, SKH, STILE, SBUF);                                              \
    asm volatile("" ::: "memory");                                              \
    __builtin_amdgcn_s_barrier();                                               \
    asm volatile("" ::: "memory");                                              \
    __builtin_amdgcn_s_setprio(1);                                              \
    _Pragma("unroll")                                                           \
    for (int mfl_=0; mfl_<2; ++mfl_)                                            \
      _Pragma("unroll")                                                         \
      for (int nf_=0; nf_<NF; ++nf_)                                            \
        _Pragma("unroll")                                                       \
        for (int k2_=0; k2_<2; ++k2_)                                           \
          acc[(MH)*2+mfl_][nf_] = __builtin_amdgcn_mfma_f32_32x32x16_bf16(      \
              af_[mfl_][k2_], bfr[k2_][nf_], acc[(MH)*2+mfl_][nf_], 0,0,0);     \
    __builtin_amdgcn_s_setprio(0);                                              \
    if (CKPT){                                                                  \
      if constexpr (LB==2) asm volatile("s_waitcnt vmcnt(4)" ::: "memory");     \
      else                 asm volatile("s_waitcnt vmcnt(3)" ::: "memory");     \
    }                                                                           \
    asm volatile("" ::: "memory");                                              \
    __builtin_amdgcn_s_barrier();                                               \
  }while(0)

  // prologue: tile0 (all 4 halves) + tile1 klo halves; counted wait keeps tile1 loads in flight
  STAGE(0,0,0,0); STAGE(1,0,0,0); STAGE(0,1,0,0); STAGE(1,1,0,0);
  STAGE(0,0,1,1); STAGE(1,0,1,1);
  if constexpr (LB==2) asm volatile("s_waitcnt vmcnt(4)" ::: "memory");
  else                 asm volatile("s_waitcnt vmcnt(3)" ::: "memory");
  asm volatile("" ::: "memory");
  __builtin_amdgcn_s_barrier();

  for (int i=0; i<niter; ++i){
    const int O  = 2*i+1;
    const int E2 = 2*i+2;
    const int O2 = 2*i+3;
    PHASE(0,0,0,true , 0,1,O ,1, false);
    PHASE(0,0,1,false, 1,1,O ,1, true );
    PHASE(0,1,0,true , 0,0,E2,0, false);
    PHASE(0,1,1,false, 1,0,E2,0, true );
    PHASE(1,0,0,true , 0,1,E2,0, false);
    PHASE(1,0,1,false, 1,1,E2,0, true );
    PHASE(1,1,0,true , 0,0,O2,1, false);
    PHASE(1,1,1,false, 1,0,O2,1, true );
  }
#undef PHASE
#undef STAGE

  // epilogue: 32x32 C/D layout col=lane&31, row=(reg&3)+8*(reg>>2)+4*(lane>>5)
  #pragma unroll
  for (int nf=0; nf<NF; ++nf){
    int col = bn + (int)wn*(BN/4) + nf*32 + (int)lc;
    float bv = bias[col];
    #pragma unroll
    for (int mf=0; mf<4; ++mf){
      #pragma unroll
      for (int reg=0; reg<16; ++reg){
        int row = bm + (int)wm*128 + mf*32 + (reg&3) + 8*(reg>>2) + 4*(int)hi;
        float v = acc[mf][nf][reg] + bv;
        C[(size_t)row*ldc + col] = f2bf(fmaxf(v, 0.f));
      }
    }
  }
}

// ---------------- embedding gather + pairwise interaction, in-place on R (B x 512 bf16)
__global__ __launch_bounds__(256) void interact(const int* __restrict__ idx,
    const float* __restrict__ emb, ushort* __restrict__ R)
{
  __shared__ __align__(16) ushort Tl[4][32][136];
  const int w = threadIdx.x>>6, l = threadIdx.x&63;
  const int b = blockIdx.x*4 + w;
  ushort* Rrow = R + (size_t)b*512;

  uint xv = ((const uint*)Rrow)[l];
  *(uint*)&Tl[w][0][2*l] = xv;

  int myidx = (l<26) ? idx[(size_t)l*B_ROWS + b] : 0;
  const int half = l>>5, lc = l&31;
  #pragma unroll
  for (int i=0;i<13;i++){
    const int row = 2*i + 1 + half;
    int e = __shfl(myidx, row - 1);
    const float4* rp = (const float4*)(emb + ((size_t)(row-1)*50000 + (size_t)e)*128);
    float4 v = rp[lc];
    uint2 pk;
    pk.x = (uint)f2bf(v.x) | ((uint)f2bf(v.y)<<16);
    pk.y = (uint)f2bf(v.z) | ((uint)f2bf(v.w)<<16);
    *(uint2*)&Tl[w][row][4*lc] = pk;
  }
  __syncthreads();

  f32x16 acc;
  #pragma unroll
  for (int i=0;i<16;i++) acc[i] = 0.f;
  #pragma unroll
  for (int kk=0;kk<8;kk++){
    short8 fa = *(const short8*)((const char*)&Tl[w][0][0] + (size_t)(l&31)*272 + kk*32 + (l>>5)*16);
    acc = __builtin_amdgcn_mfma_f32_32x32x16_bf16(fa, fa, acc, 0,0,0);
  }

  const int c = l&31;
  #pragma unroll
  for (int j=0;j<16;j++){
    int r = (j&3) + 8*(j>>2) + 4*(l>>5);
    if (c < r && r <= 26) Rrow[128 + r*(r-1)/2 + c] = f2bf(acc[j]);
  }
  if (l < 33) Rrow[479 + l] = 0;
}

// ---------------- final: sigmoid(h3 @ w + b), clip -> fp32 out
__global__ __launch_bounds__(256) void finlayer(const ushort* __restrict__ h3,
    const ushort* __restrict__ wt, const float* __restrict__ b3, float* __restrict__ out)
{
  int w = threadIdx.x>>6, l = threadIdx.x&63;
  int b = blockIdx.x*4 + w;
  short8 hv = *(const short8*)(h3 + (size_t)b*512 + l*8);
  short8 wv = *(const short8*)(wt + l*8);
  float s = 0.f;
  #pragma unroll
  for (int j=0;j<8;j++) s += bf2f((ushort)hv[j])*bf2f((ushort)wv[j]);
  #pragma unroll
  for (int off=32; off>0; off>>=1) s += __shfl_xor(s, off);
  if (l==0){
    float h = s + b3[0];
    float p = 1.f/(1.f + expf(-h));
    out[b] = fminf(fmaxf(p, 0.f), 1.f);
  }
}

extern "C" void kernel_launch(void* const* d_in, const int* in_sizes, int n_in,
                              void* d_out, int out_size, void* d_ws, size_t ws_size,
                              hipStream_t stream)
{
  const float* dense_x = (const float*)d_in[0];
  const int*   indices = (const int*)d_in[1];
  const float* emb     = (const float*)d_in[2];
  const float* bW0 = (const float*)d_in[3];  const float* bb0 = (const float*)d_in[4];
  const float* bW1 = (const float*)d_in[5];  const float* bb1 = (const float*)d_in[6];
  const float* bW2 = (const float*)d_in[7];  const float* bb2 = (const float*)d_in[8];
  const float* tW0 = (const float*)d_in[9];  const float* tb0 = (const float*)d_in[10];
  const float* tW1 = (const float*)d_in[11]; const float* tb1 = (const float*)d_in[12];
  const float* tW2 = (const float*)d_in[13]; const float* tb2 = (const float*)d_in[14];
  const float* tW3 = (const float*)d_in[15]; const float* tb3 = (const float*)d_in[16];
  float* out = (float*)d_out;
  const int Bn = B_ROWS;

  char* ws = (char*)d_ws;
  size_t o = 0;
  auto alloc = [&](size_t bytes)->char*{ char* r = ws + o; o += (bytes + 255) & ~(size_t)255; return r; };
  ushort* wtB1 = (ushort*)alloc(256*512*2);
  ushort* wtB2 = (ushort*)alloc(128*256*2);
  ushort* wtT0 = (ushort*)alloc(1024*512*2);
  ushort* wtT1 = (ushort*)alloc((size_t)1024*1024*2);
  ushort* wtT2 = (ushort*)alloc(512*1024*2);
  ushort* wtT3 = (ushort*)alloc(512*2);
  ushort* P    = (ushort*)alloc((size_t)Bn*512*2);
  ushort* act1 = (ushort*)alloc((size_t)Bn*256*2);
  ushort* h1   = (ushort*)alloc((size_t)Bn*1024*2);
  ushort* h2   = (ushort*)alloc((size_t)Bn*1024*2);
  (void)ws_size; (void)in_sizes; (void)n_in; (void)out_size;

  TArgs6 ta;
  ta.a[0] = { bW1, wtB1, 512 , 256 , 512  };
  ta.a[1] = { bW2, wtB2, 256 , 128 , 256  };
  ta.a[2] = { tW0, wtT0, 479 , 1024, 512  };
  ta.a[3] = { tW1, wtT1, 1024, 1024, 1024 };
  ta.a[4] = { tW2, wtT2, 1024, 512 , 1024 };
  ta.a[5] = { tW3, wtT3, 0   , 512 , 0    };   // K==0 -> plain copy-convert
  transp_tiled<<<dim3(32,32,6),256,0,stream>>>(ta);

  // bottom MLP (bot2 writes x directly into R rows, ldc=512)
  bot0<<<Bn*512/256,256,0,stream>>>(dense_x, bW0, bb0, P);
  gemm_bt<4,true><<<dim3(128,2),256,0,stream>>>(P,    wtB1, bb1, act1, Bn,256,512, 256);
  gemm_bt<2,true><<<dim3(256,1),256,0,stream>>>(act1, wtB2, bb2, P,    Bn,128,256, 512);

  // gather + interaction in place on R (= P)
  interact<<<Bn/4,256,0,stream>>>(indices, emb, P);

  // top MLP: deep-pipelined 256-tile GEMMs (32x32x16 MFMA)
  gemm256<256><<<dim3(64,4),512,0,stream>>>(P,  wtT0, tb0, h1, 512 , 1024);
  gemm256<256><<<dim3(64,4),512,0,stream>>>(h1, wtT1, tb1, h2, 1024, 1024);
  gemm256<128><<<dim3(64,4),512,0,stream>>>(h2, wtT2, tb2, P,  1024, 512);
  finlayer<<<Bn/4,256,0,stream>>>(P, wtT3, tb3, out);
}